// Round 9
// baseline (2669.605 us; speedup 1.0000x reference)
//
#include <hip/hip_runtime.h>
#include <hip/hip_bf16.h>

// RL2 LSTM fused kernel, round 9.
// r8 A/B proved the 6.4us/step is LATENCY-chain-bound (poll backoff changed
// traffic but not time). r9 = r4/r8's proven per-step body wrapped in a
// 4-slice rotation: 64 blocks = 8 hidden-chunks x 8 slice-groups, each block
// time-multiplexes 4 independent batch slices (64 rows). While slice s waits
// for peer h to transit the MALL, the block computes slices s+1..s+3 -- the
// round-trip leaves the critical path. Protocol, hdb layout, tag check,
// publish path, barrier structure are UNCHANGED from the twice-proven r4.
// Deltas: b0 per-slice; hstage[slice][parity]; part parity = s&1; c-state in
// a fully-unrolled per-slice array (static indices); split vmcnt(14)/vmcnt(0)
// so x-MFMAs overlap poll flight.

#define WS_TT   0u
#define WS_CT   409600u
#define WS_AT   819200u
#define WS_WD1  825344u
#define WS_B1T  829440u
#define WS_WRW  830464u
#define WS_WDN  831488u
#define WS_W2T  1048576u   // 1024 pc x 512 k bf16, swizzled: 1MB
#define WS_HDB  2097152u   // ring: 2 x 512 x 256 tagged dwords = 1MB
#define WS_X    4194304u   // 65536 x 256 bf16 = 32MB
#define WS_NEED (WS_X + 33554432u)

typedef __attribute__((ext_vector_type(8))) short s8v;
typedef __attribute__((ext_vector_type(4))) float f4v;
typedef __attribute__((ext_vector_type(4))) unsigned u4v;
typedef unsigned short u16;
typedef unsigned char u8;

union U4 { u4v v4; unsigned u[4]; };

__device__ __forceinline__ float sigm_(float x) {
  return __builtin_amdgcn_rcpf(1.f + __expf(-x));
}
__device__ __forceinline__ float tanh_(float x) {
  return 1.f - 2.f * __builtin_amdgcn_rcpf(1.f + __expf(2.f * x));
}

// ---------------- fused prep: tables + W2T + h0/bias init -------------------
__global__ __launch_bounds__(256) void k_prep(
    const float* tile_emb, const float* color_emb, const float* action_emb,
    const float* Wdir, const float* bdir, const float* W1, const float* b1,
    const float* Wx, const float* Wh, const float* h0, const float* bpi,
    const float* bv, float* out, char* ws) {
  int id = blockIdx.x;
  int h = threadIdx.x;
  if (id < 816) {
    // ---- encoder tables ----
    float* TT  = (float*)(ws + WS_TT);
    float* CT  = (float*)(ws + WS_CT);
    float* AT  = (float*)(ws + WS_AT);
    float* WD1 = (float*)(ws + WS_WD1);
    float* B1T = (float*)(ws + WS_B1T);
    float* WRW = (float*)(ws + WS_WRW);
    float* WDN = (float*)(ws + WS_WDN);
    if (id < 400) {                 // Ttab[p][v][h]
      int p = id >> 4, v = id & 15;
      float s = 0.f;
#pragma unroll
      for (int e = 0; e < 16; ++e) s += tile_emb[v * 16 + e] * W1[(p * 32 + e) * 256 + h];
      TT[id * 256 + h] = s;
    } else if (id < 800) {          // Ctab[p][v][h]
      int p = (id - 400) >> 4, v = id & 15;
      float s = 0.f;
#pragma unroll
      for (int e = 0; e < 16; ++e) s += color_emb[v * 16 + e] * W1[(p * 32 + 16 + e) * 256 + h];
      CT[(id - 400) * 256 + h] = s;
    } else {
      int r = id - 800;
      if (r < 6) {
        float s = 0.f;
#pragma unroll
        for (int e = 0; e < 16; ++e) s += action_emb[r * 16 + e] * W1[(816 + e) * 256 + h];
        AT[r * 256 + h] = s;
      } else if (r < 10) {
        int d = r - 6;
        float s = 0.f;
#pragma unroll
        for (int e = 0; e < 16; ++e) s += Wdir[d * 16 + e] * W1[(800 + e) * 256 + h];
        WD1[d * 256 + h] = s;
      } else if (r == 10) {
        float s = b1[h];
#pragma unroll
        for (int e = 0; e < 16; ++e) s += bdir[e] * W1[(800 + e) * 256 + h];
        B1T[h] = s;
      } else if (r == 11) {
        WRW[h] = W1[832 * 256 + h];
      } else if (r == 12) {
        WDN[h] = W1[833 * 256 + h];
      }
    }
  } else if (id < 944) {
    // ---- W2T = [Wx;Wh]^T bf16, pc-permuted, LDS-XOR-preswizzled ----
    int wb = id - 816;
#pragma unroll
    for (int kk = 0; kk < 4; ++kk) {
      int k = wb * 4 + kk;
      const float* row = (k < 256) ? (Wx + (size_t)k * 1024)
                                   : (Wh + (size_t)(k - 256) * 1024);
      float4 v4 = *(const float4*)(row + h * 4);
      float vv[4] = {v4.x, v4.y, v4.z, v4.w};
#pragma unroll
      for (int e = 0; e < 4; ++e) {
        int n = h * 4 + e;
        int gate = n >> 8, rem = n & 255;
        int q = rem >> 5, jl = rem & 31;
        int pcl = (jl >> 2) * 16 + (jl & 3) * 4 + gate;
        unsigned byteoff = ((unsigned)(pcl << 10) + (unsigned)(k << 1)) ^
                           (((unsigned)(pcl & 7)) << 4);
        __hip_bfloat16 bv16 = __float2bfloat16(vv[e]);
        *(u16*)(ws + WS_W2T + (size_t)q * 131072u + byteoff) = *(u16*)&bv16;
      }
    }
  } else {
    // ---- misc init ----
    int mb = id - 944;
    int i = mb * 256 + h;
    if (mb < 512) {                       // h0 -> tagged dwords, tag 0
      unsigned* hdb = (unsigned*)(ws + WS_HDB);
      __hip_bfloat16 hb = __float2bfloat16(h0[i]);
      hdb[i] = (unsigned)*(u16*)&hb;      // tag = 0 in high bits
    } else if (mb < 2048) {               // logits = bpi
      int j = i - 131072;
      out[j] = bpi[j % 6];
    } else {                              // values = bv
      int j = i - 524288;
      out[393216 + j] = bv[0];
    }
  }
}

// ---------------- x = relu(enc @ W1 + b1)  via tables -----------------------
__global__ __launch_bounds__(512, 1) void k_x(
    const int* obs_img, const float* obs_dir, const int* prev_action,
    const float* prev_reward, const float* done, char* ws) {
  __shared__ float TtL[12800];   // [25*16][32]
  __shared__ float CtL[12800];
  __shared__ float AtL[192];
  __shared__ float WdL[128];
  __shared__ u8 pkT[6400];       // [256 tb][25]
  __shared__ u8 pkC[6400];
  __shared__ u8 actL[256];
  __shared__ float rewL[256];
  __shared__ float dnL[256];
  __shared__ float dirL[1024];

  const float* TT  = (const float*)(ws + WS_TT);
  const float* CT  = (const float*)(ws + WS_CT);
  const float* AT  = (const float*)(ws + WS_AT);
  const float* WD1 = (const float*)(ws + WS_WD1);
  const float* B1T = (const float*)(ws + WS_B1T);
  const float* WRW = (const float*)(ws + WS_WRW);
  const float* WDN = (const float*)(ws + WS_WDN);
  __hip_bfloat16* xout = (__hip_bfloat16*)(ws + WS_X);

  int bid = blockIdx.x;          // 512 blocks
  int slice = bid & 7, grp = bid >> 3;   // 64 groups x 1024 tb
  int h0 = slice * 32;
  int tid = threadIdx.x;
  int sub = tid >> 5, hh = tid & 31;

  for (int e = tid; e < 12800; e += 512) {
    int pv = e >> 5, k = e & 31;
    TtL[e] = TT[pv * 256 + h0 + k];
    CtL[e] = CT[pv * 256 + h0 + k];
  }
  for (int e = tid; e < 192; e += 512) AtL[e] = AT[(e >> 5) * 256 + h0 + (e & 31)];
  for (int e = tid; e < 128; e += 512) WdL[e] = WD1[(e >> 5) * 256 + h0 + (e & 31)];
  float b1r = B1T[h0 + hh], wrr = WRW[h0 + hh], wdr = WDN[h0 + hh];

  for (int cg = 0; cg < 4; ++cg) {
    int tb0 = grp * 1024 + cg * 256;
    __syncthreads();
    for (int e = tid; e < 6400; e += 512) {
      int tbl = e / 25, p = e - tbl * 25;
      int base = ((tb0 + tbl) * 25 + p) * 2;
      pkT[e] = (u8)obs_img[base];
      pkC[e] = (u8)obs_img[base + 1];
    }
    for (int e = tid; e < 256; e += 512) {
      actL[e] = (u8)prev_action[tb0 + e];
      rewL[e] = prev_reward[tb0 + e];
      dnL[e]  = done[tb0 + e];
    }
    for (int e = tid; e < 1024; e += 512) dirL[e] = obs_dir[(size_t)tb0 * 4 + e];
    __syncthreads();

    for (int pass = 0; pass < 16; ++pass) {
      int tbl = pass * 16 + sub;
      float s0 = b1r, s1 = 0.f;
#pragma unroll
      for (int p = 0; p < 25; ++p) {
        int tv = pkT[tbl * 25 + p];
        int cv = pkC[tbl * 25 + p];
        s0 += TtL[(p * 16 + tv) * 32 + hh];
        s1 += CtL[(p * 16 + cv) * 32 + hh];
      }
      s0 += AtL[(int)actL[tbl] * 32 + hh];
      float d0 = dirL[tbl * 4 + 0], d1 = dirL[tbl * 4 + 1];
      float d2 = dirL[tbl * 4 + 2], d3 = dirL[tbl * 4 + 3];
      s1 += d0 * WdL[hh] + d1 * WdL[32 + hh] + d2 * WdL[64 + hh] + d3 * WdL[96 + hh];
      s0 += rewL[tbl] * wrr + dnL[tbl] * wdr;
      float xv = fmaxf(s0 + s1, 0.f);
      xout[(size_t)(tb0 + tbl) * 256 + h0 + hh] = __float2bfloat16(xv);
    }
  }
}

// ---------------- persistent fused LSTM (4-slice rotation) ------------------
__global__ __launch_bounds__(256, 1) void k_lstm(
    const float* c0, const float* bh, const float* Wpi, const float* Wv,
    float* out, char* ws) {
  __shared__ u16 W2T[65536];            // 128KB: [128 pc][512 k], XOR-swizzled
  __shared__ float WpiL[32][8];         // [j-local][a]; a=6 is Wv
  __shared__ float part[2][4][16][8];   // logits partials, dbuf by s&1
  __shared__ unsigned hstage[4][2][576]; // [slice][parity][16*36] tagged h

  const u16* xbf = (const u16*)(ws + WS_X);
  unsigned* hdb = (unsigned*)(ws + WS_HDB);  // tagged dwords [2][512 b][256 j]
  const u16* w2src = (const u16*)(ws + WS_W2T);

  const int tid = threadIdx.x;
  const int bid = blockIdx.x;           // 64 blocks
  const int g = bid & 7;                // slice-group (batch rows g*64..g*64+63)
  const int q = bid >> 3;               // hidden chunk (j in [q*32, q*32+32))
  const int lane = tid & 63, wv = tid >> 6;
  const int G = lane >> 4, bl = lane & 15;

  {  // stage W2T slice (once)
    const s8v* src = (const s8v*)(w2src + (size_t)q * 65536);
    s8v* dst = (s8v*)W2T;
    for (int i = tid; i < 8192; i += 256) dst[i] = src[i];
  }
  {
    int jl = tid >> 3, a = tid & 7;
    int j = q * 32 + jl;
    WpiL[jl][a] = (a < 6) ? Wpi[j * 6 + a] : ((a == 6) ? Wv[j] : 0.f);
  }
  __syncthreads();

  const int jt0 = wv * 2, jt1 = wv * 2 + 1;
  const int jl0 = jt0 * 4 + G, jl1 = jt1 * 4 + G;
  const int myhj0 = q * 32 + jl0, myhj1 = q * 32 + jl1;
  const unsigned swz = ((unsigned)(bl & 7)) << 4;
  const unsigned ab0 = ((unsigned)(jt0 * 16 + bl)) << 10;
  const unsigned ab1 = ((unsigned)(jt1 * 16 + bl)) << 10;

  float bh0r[4], bh1r[4];
#pragma unroll
  for (int r = 0; r < 4; ++r) {
    bh0r[r] = bh[r * 256 + myhj0];
    bh1r[r] = bh[r * 256 + myhj1];
  }
  float cs0[4], cs1[4];
#pragma unroll
  for (int s = 0; s < 4; ++s) {
    int b0s = (g * 4 + s) * 16;
    cs0[s] = c0[(size_t)(b0s + bl) * 256 + myhj0];
    cs1[s] = c0[(size_t)(b0s + bl) * 256 + myhj1];
  }

  float* out_logits = out;
  float* out_values = out + 393216;
  float* out_cf = out + 458752;
  float* out_hf = out + 589824;

  for (int t = 0; t < 128; ++t) {
    const unsigned tq = (unsigned)t;
#pragma unroll
    for (int s = 0; s < 4; ++s) {
      const int b0s = (g * 4 + s) * 16;
      // ---- 1) issue x-frag loads then poll loads, back to back
      s8v xf[8];
      const u16* xr = xbf + ((size_t)t * 512 + (b0s + bl)) * 256 + 8 * G;
#pragma unroll
      for (int ks = 0; ks < 8; ++ks)
        asm volatile("global_load_dwordx4 %0, %1, off"
                     : "=v"(xf[ks]) : "v"(xr + ks * 32));

      U4 qv[16];
      const unsigned* hp = hdb + (size_t)(t & 1) * 131072u +
                           (size_t)(b0s + bl) * 256u + (unsigned)(G * 8);
#pragma unroll
      for (int i = 0; i < 16; ++i) {
        if ((i >> 1) != q || t == 0)   // own chunk comes from LDS when t>0
          asm volatile("global_load_dwordx4 %0, %1, off sc0 sc1"
                       : "=v"(qv[i].v4) : "v"(hp + (i >> 1) * 32 + (i & 1) * 4));
      }
      // x loads (issued first) retire in order: waiting to <=14 outstanding
      // guarantees all 8 x loads done; poll loads may still be in flight.
      asm volatile("s_waitcnt vmcnt(14)" ::: "memory");
      __builtin_amdgcn_sched_barrier(0);

      // ---- 2) x-MFMAs overlap the poll flight
      f4v acc0 = {0.f, 0.f, 0.f, 0.f};
      f4v acc1 = {0.f, 0.f, 0.f, 0.f};
#pragma unroll
      for (int ks = 0; ks < 8; ++ks) {
        unsigned k2 = (unsigned)(ks * 64 + G * 16);
        s8v a0 = *(const s8v*)((const char*)W2T + ((ab0 + k2) ^ swz));
        s8v a1 = *(const s8v*)((const char*)W2T + ((ab1 + k2) ^ swz));
        acc0 = __builtin_amdgcn_mfma_f32_16x16x32_bf16(a0, xf[ks], acc0, 0, 0, 0);
        acc1 = __builtin_amdgcn_mfma_f32_16x16x32_bf16(a1, xf[ks], acc1, 0, 0, 0);
      }
      asm volatile("s_waitcnt vmcnt(0)" ::: "memory");
      __builtin_amdgcn_sched_barrier(0);

      // ---- 3) tag check + re-poll (s_sleep backoff)
      bool ok = true;
#pragma unroll
      for (int i = 0; i < 16; ++i) {
        if ((i >> 1) == q && t != 0) continue;
#pragma unroll
        for (int c2 = 0; c2 < 4; ++c2) ok &= ((qv[i].u[c2] >> 16) == tq);
      }
      while (!ok) {
        __builtin_amdgcn_s_sleep(2);
#pragma unroll
        for (int i = 0; i < 16; ++i) {
          if ((i >> 1) != q || t == 0)
            asm volatile("global_load_dwordx4 %0, %1, off sc0 sc1"
                         : "=v"(qv[i].v4) : "v"(hp + (i >> 1) * 32 + (i & 1) * 4));
        }
        asm volatile("s_waitcnt vmcnt(0)" ::: "memory");
        __builtin_amdgcn_sched_barrier(0);
        ok = true;
#pragma unroll
        for (int i = 0; i < 16; ++i) {
          if ((i >> 1) == q && t != 0) continue;
#pragma unroll
          for (int c2 = 0; c2 < 4; ++c2) ok &= ((qv[i].u[c2] >> 16) == tq);
        }
      }

      // ---- 4) h-MFMAs (own chunk from hstage[s][t&1])
#pragma unroll
      for (int ks = 0; ks < 8; ++ks) {
        union { s8v v; unsigned u[4]; } bu;
        if (ks == q && t != 0) {
          const unsigned* hs = &hstage[s][t & 1][bl * 36 + G * 8];
          bu.u[0] = (hs[0] & 0xffffu) | (hs[1] << 16);
          bu.u[1] = (hs[2] & 0xffffu) | (hs[3] << 16);
          bu.u[2] = (hs[4] & 0xffffu) | (hs[5] << 16);
          bu.u[3] = (hs[6] & 0xffffu) | (hs[7] << 16);
        } else {
          const unsigned* pa = qv[ks * 2].u;
          const unsigned* pb = qv[ks * 2 + 1].u;
          bu.u[0] = (pa[0] & 0xffffu) | (pa[1] << 16);
          bu.u[1] = (pa[2] & 0xffffu) | (pa[3] << 16);
          bu.u[2] = (pb[0] & 0xffffu) | (pb[1] << 16);
          bu.u[3] = (pb[2] & 0xffffu) | (pb[3] << 16);
        }
        unsigned k2 = (unsigned)((ks + 8) * 64 + G * 16);
        s8v a0 = *(const s8v*)((const char*)W2T + ((ab0 + k2) ^ swz));
        s8v a1 = *(const s8v*)((const char*)W2T + ((ab1 + k2) ^ swz));
        acc0 = __builtin_amdgcn_mfma_f32_16x16x32_bf16(a0, bu.v, acc0, 0, 0, 0);
        acc1 = __builtin_amdgcn_mfma_f32_16x16x32_bf16(a1, bu.v, acc1, 0, 0, 0);
      }

      // ---- 5) gates (lane-local; per-slice c state, static index)
      float zi0 = acc0[0] + bh0r[0], zf0 = acc0[1] + bh0r[1];
      float zg0 = acc0[2] + bh0r[2], zo0 = acc0[3] + bh0r[3];
      float cn0 = sigm_(zf0) * cs0[s] + sigm_(zi0) * tanh_(zg0);
      float hn0 = sigm_(zo0) * tanh_(cn0);
      cs0[s] = cn0;
      float zi1 = acc1[0] + bh1r[0], zf1 = acc1[1] + bh1r[1];
      float zg1 = acc1[2] + bh1r[2], zo1 = acc1[3] + bh1r[3];
      float cn1 = sigm_(zf1) * cs1[s] + sigm_(zi1) * tanh_(zg1);
      float hn1 = sigm_(zo1) * tanh_(cn1);
      cs1[s] = cn1;

      // ---- 6) stage tagged h in LDS + logits partials
      const int wslot = (t + 1) & 1, pt = s & 1;
      if (t < 127) {
        __hip_bfloat16 hb0 = __float2bfloat16(hn0);
        __hip_bfloat16 hb1 = __float2bfloat16(hn1);
        hstage[s][wslot][bl * 36 + jl0] =
            ((unsigned)(t + 1) << 16) | (unsigned)*(u16*)&hb0;
        hstage[s][wslot][bl * 36 + jl1] =
            ((unsigned)(t + 1) << 16) | (unsigned)*(u16*)&hb1;
      } else {
        size_t o = (size_t)(b0s + bl) * 256;
        out_cf[o + myhj0] = cs0[s];
        out_cf[o + myhj1] = cs1[s];
        out_hf[o + myhj0] = hn0;
        out_hf[o + myhj1] = hn1;
      }
      float pl[7];
#pragma unroll
      for (int a = 0; a < 7; ++a) {
        float sv = hn0 * WpiL[jl0][a] + hn1 * WpiL[jl1][a];
        sv += __shfl_xor(sv, 16, 64);
        sv += __shfl_xor(sv, 32, 64);
        pl[a] = sv;
      }
      if (lane < 16) {
#pragma unroll
        for (int a = 0; a < 7; ++a) part[pt][wv][bl][a] = pl[a];
      }

      __syncthreads();

      // ---- 7) publish (waves 0-1) || logits adds (waves 2-3)
      if (tid < 128) {
        if (t < 127) {
          int b_ = tid >> 3, quad = tid & 7;
          U4 v;
          v.u[0] = hstage[s][wslot][b_ * 36 + quad * 4 + 0];
          v.u[1] = hstage[s][wslot][b_ * 36 + quad * 4 + 1];
          v.u[2] = hstage[s][wslot][b_ * 36 + quad * 4 + 2];
          v.u[3] = hstage[s][wslot][b_ * 36 + quad * 4 + 3];
          unsigned* dst = hdb + (size_t)wslot * 131072u +
                          (size_t)(b0s + b_) * 256u + (unsigned)(q * 32 + quad * 4);
          asm volatile("global_store_dwordx4 %0, %1, off sc0 sc1"
                       :: "v"(dst), "v"(v.v4) : "memory");
        }
      } else {
        int i2 = tid - 128, b_ = i2 >> 3, a_ = i2 & 7;
        if (a_ < 7) {
          float sv = part[pt][0][b_][a_] + part[pt][1][b_][a_] +
                     part[pt][2][b_][a_] + part[pt][3][b_][a_];
          if (a_ < 6)
            atomicAdd(out_logits + ((size_t)t * 512 + b0s + b_) * 6 + a_, sv);
          else
            atomicAdd(out_values + (size_t)t * 512 + b0s + b_, sv);
        }
      }
    }  // slice loop
  }    // t loop
}

extern "C" void kernel_launch(void* const* d_in, const int* in_sizes, int n_in,
                              void* d_out, int out_size, void* d_ws, size_t ws_size,
                              hipStream_t stream) {
  const int*   obs_img     = (const int*)d_in[0];
  const float* obs_dir     = (const float*)d_in[1];
  const int*   prev_action = (const int*)d_in[2];
  const float* prev_reward = (const float*)d_in[3];
  const float* done        = (const float*)d_in[4];
  const float* c0          = (const float*)d_in[5];
  const float* h0          = (const float*)d_in[6];
  const float* tile_emb    = (const float*)d_in[7];
  const float* color_emb   = (const float*)d_in[8];
  const float* action_emb  = (const float*)d_in[9];
  const float* Wdir        = (const float*)d_in[10];
  const float* bdir        = (const float*)d_in[11];
  const float* W1          = (const float*)d_in[12];
  const float* b1          = (const float*)d_in[13];
  const float* Wx          = (const float*)d_in[14];
  const float* Wh          = (const float*)d_in[15];
  const float* bh          = (const float*)d_in[16];
  const float* Wpi         = (const float*)d_in[17];
  const float* bpi         = (const float*)d_in[18];
  const float* Wv          = (const float*)d_in[19];
  const float* bv          = (const float*)d_in[20];
  (void)in_sizes; (void)n_in; (void)out_size; (void)ws_size;

  char* ws = (char*)d_ws;
  float* out = (float*)d_out;

  // kill stale tags every launch (0xAAAA never matches a real tag 0..128)
  (void)hipMemsetAsync(ws + WS_HDB, 0xAA, 1048576u, stream);
  k_prep<<<3248, 256, 0, stream>>>(tile_emb, color_emb, action_emb, Wdir, bdir,
                                   W1, b1, Wx, Wh, h0, bpi, bv, out, ws);
  k_x<<<512, 512, 0, stream>>>(obs_img, obs_dir, prev_action, prev_reward, done, ws);
  k_lstm<<<64, 256, 0, stream>>>(c0, bh, Wpi, Wv, out, ws);
}

// Round 10
// 1023.774 us; speedup vs baseline: 2.6076x; 2.6076x over previous
//
#include <hip/hip_runtime.h>
#include <hip/hip_bf16.h>

// RL2 LSTM fused kernel, round 10.
// = r8 (proven 818us k_lstm) + two protocol-invariant timing changes:
//  (A) EARLY PER-LANE PUBLISH: the 2 tagged sc01 dword stores issue straight
//      from registers right after the gate math -- before the logits shfl,
//      part[] stores, and barrier. Visibility starts ~0.5-1us earlier and
//      overlaps the logits tail. (Old waves0-1 LDS->global publish removed.)
//      Ring safety unchanged: tag-(t+1) writes happen only after this wave
//      detected tag t => all peers finished their tag-(t-1) reads of the slot.
//  (B) VMCNT SPLIT: x loads first, then polls; vmcnt(14) -> x-MFMAs overlap
//      the first poll flight -> vmcnt(0) -> tag check.
// r9's 4-slice rotation regressed 3x (convoy; 29 failed rounds/slice-step)
// and is abandoned. Everything else is byte-identical to r8.

#define WS_TT   0u
#define WS_CT   409600u
#define WS_AT   819200u
#define WS_WD1  825344u
#define WS_B1T  829440u
#define WS_WRW  830464u
#define WS_WDN  831488u
#define WS_W2T  1048576u   // 1024 pc x 512 k bf16, swizzled: 1MB
#define WS_HDB  2097152u   // ring: 2 x 512 x 256 tagged dwords = 1MB
#define WS_X    4194304u   // 65536 x 256 bf16 = 32MB
#define WS_NEED (WS_X + 33554432u)

typedef __attribute__((ext_vector_type(8))) short s8v;
typedef __attribute__((ext_vector_type(4))) float f4v;
typedef __attribute__((ext_vector_type(4))) unsigned u4v;
typedef unsigned short u16;
typedef unsigned char u8;

union U4 { u4v v4; unsigned u[4]; };

__device__ __forceinline__ float sigm_(float x) {
  return __builtin_amdgcn_rcpf(1.f + __expf(-x));
}
__device__ __forceinline__ float tanh_(float x) {
  return 1.f - 2.f * __builtin_amdgcn_rcpf(1.f + __expf(2.f * x));
}

// ---------------- fused prep: tables + W2T + h0/bias init -------------------
__global__ __launch_bounds__(256) void k_prep(
    const float* tile_emb, const float* color_emb, const float* action_emb,
    const float* Wdir, const float* bdir, const float* W1, const float* b1,
    const float* Wx, const float* Wh, const float* h0, const float* bpi,
    const float* bv, float* out, char* ws) {
  int id = blockIdx.x;
  int h = threadIdx.x;
  if (id < 816) {
    // ---- encoder tables ----
    float* TT  = (float*)(ws + WS_TT);
    float* CT  = (float*)(ws + WS_CT);
    float* AT  = (float*)(ws + WS_AT);
    float* WD1 = (float*)(ws + WS_WD1);
    float* B1T = (float*)(ws + WS_B1T);
    float* WRW = (float*)(ws + WS_WRW);
    float* WDN = (float*)(ws + WS_WDN);
    if (id < 400) {                 // Ttab[p][v][h]
      int p = id >> 4, v = id & 15;
      float s = 0.f;
#pragma unroll
      for (int e = 0; e < 16; ++e) s += tile_emb[v * 16 + e] * W1[(p * 32 + e) * 256 + h];
      TT[id * 256 + h] = s;
    } else if (id < 800) {          // Ctab[p][v][h]
      int p = (id - 400) >> 4, v = id & 15;
      float s = 0.f;
#pragma unroll
      for (int e = 0; e < 16; ++e) s += color_emb[v * 16 + e] * W1[(p * 32 + 16 + e) * 256 + h];
      CT[(id - 400) * 256 + h] = s;
    } else {
      int r = id - 800;
      if (r < 6) {
        float s = 0.f;
#pragma unroll
        for (int e = 0; e < 16; ++e) s += action_emb[r * 16 + e] * W1[(816 + e) * 256 + h];
        AT[r * 256 + h] = s;
      } else if (r < 10) {
        int d = r - 6;
        float s = 0.f;
#pragma unroll
        for (int e = 0; e < 16; ++e) s += Wdir[d * 16 + e] * W1[(800 + e) * 256 + h];
        WD1[d * 256 + h] = s;
      } else if (r == 10) {
        float s = b1[h];
#pragma unroll
        for (int e = 0; e < 16; ++e) s += bdir[e] * W1[(800 + e) * 256 + h];
        B1T[h] = s;
      } else if (r == 11) {
        WRW[h] = W1[832 * 256 + h];
      } else if (r == 12) {
        WDN[h] = W1[833 * 256 + h];
      }
    }
  } else if (id < 944) {
    // ---- W2T = [Wx;Wh]^T bf16, pc-permuted, LDS-XOR-preswizzled ----
    int wb = id - 816;
#pragma unroll
    for (int kk = 0; kk < 4; ++kk) {
      int k = wb * 4 + kk;
      const float* row = (k < 256) ? (Wx + (size_t)k * 1024)
                                   : (Wh + (size_t)(k - 256) * 1024);
      float4 v4 = *(const float4*)(row + h * 4);
      float vv[4] = {v4.x, v4.y, v4.z, v4.w};
#pragma unroll
      for (int e = 0; e < 4; ++e) {
        int n = h * 4 + e;
        int gate = n >> 8, rem = n & 255;
        int q = rem >> 5, jl = rem & 31;
        int pcl = (jl >> 2) * 16 + (jl & 3) * 4 + gate;
        unsigned byteoff = ((unsigned)(pcl << 10) + (unsigned)(k << 1)) ^
                           (((unsigned)(pcl & 7)) << 4);
        __hip_bfloat16 bv16 = __float2bfloat16(vv[e]);
        *(u16*)(ws + WS_W2T + (size_t)q * 131072u + byteoff) = *(u16*)&bv16;
      }
    }
  } else {
    // ---- misc init ----
    int mb = id - 944;
    int i = mb * 256 + h;
    if (mb < 512) {                       // h0 -> tagged dwords, tag 0
      unsigned* hdb = (unsigned*)(ws + WS_HDB);
      __hip_bfloat16 hb = __float2bfloat16(h0[i]);
      hdb[i] = (unsigned)*(u16*)&hb;      // tag = 0 in high bits
    } else if (mb < 2048) {               // logits = bpi
      int j = i - 131072;
      out[j] = bpi[j % 6];
    } else {                              // values = bv
      int j = i - 524288;
      out[393216 + j] = bv[0];
    }
  }
}

// ---------------- x = relu(enc @ W1 + b1)  via tables -----------------------
__global__ __launch_bounds__(512, 1) void k_x(
    const int* obs_img, const float* obs_dir, const int* prev_action,
    const float* prev_reward, const float* done, char* ws) {
  __shared__ float TtL[12800];   // [25*16][32]
  __shared__ float CtL[12800];
  __shared__ float AtL[192];
  __shared__ float WdL[128];
  __shared__ u8 pkT[6400];       // [256 tb][25]
  __shared__ u8 pkC[6400];
  __shared__ u8 actL[256];
  __shared__ float rewL[256];
  __shared__ float dnL[256];
  __shared__ float dirL[1024];

  const float* TT  = (const float*)(ws + WS_TT);
  const float* CT  = (const float*)(ws + WS_CT);
  const float* AT  = (const float*)(ws + WS_AT);
  const float* WD1 = (const float*)(ws + WS_WD1);
  const float* B1T = (const float*)(ws + WS_B1T);
  const float* WRW = (const float*)(ws + WS_WRW);
  const float* WDN = (const float*)(ws + WS_WDN);
  __hip_bfloat16* xout = (__hip_bfloat16*)(ws + WS_X);

  int bid = blockIdx.x;          // 512 blocks
  int slice = bid & 7, grp = bid >> 3;   // 64 groups x 1024 tb
  int h0 = slice * 32;
  int tid = threadIdx.x;
  int sub = tid >> 5, hh = tid & 31;

  for (int e = tid; e < 12800; e += 512) {
    int pv = e >> 5, k = e & 31;
    TtL[e] = TT[pv * 256 + h0 + k];
    CtL[e] = CT[pv * 256 + h0 + k];
  }
  for (int e = tid; e < 192; e += 512) AtL[e] = AT[(e >> 5) * 256 + h0 + (e & 31)];
  for (int e = tid; e < 128; e += 512) WdL[e] = WD1[(e >> 5) * 256 + h0 + (e & 31)];
  float b1r = B1T[h0 + hh], wrr = WRW[h0 + hh], wdr = WDN[h0 + hh];

  for (int cg = 0; cg < 4; ++cg) {
    int tb0 = grp * 1024 + cg * 256;
    __syncthreads();
    for (int e = tid; e < 6400; e += 512) {
      int tbl = e / 25, p = e - tbl * 25;
      int base = ((tb0 + tbl) * 25 + p) * 2;
      pkT[e] = (u8)obs_img[base];
      pkC[e] = (u8)obs_img[base + 1];
    }
    for (int e = tid; e < 256; e += 512) {
      actL[e] = (u8)prev_action[tb0 + e];
      rewL[e] = prev_reward[tb0 + e];
      dnL[e]  = done[tb0 + e];
    }
    for (int e = tid; e < 1024; e += 512) dirL[e] = obs_dir[(size_t)tb0 * 4 + e];
    __syncthreads();

    for (int pass = 0; pass < 16; ++pass) {
      int tbl = pass * 16 + sub;
      float s0 = b1r, s1 = 0.f;
#pragma unroll
      for (int p = 0; p < 25; ++p) {
        int tv = pkT[tbl * 25 + p];
        int cv = pkC[tbl * 25 + p];
        s0 += TtL[(p * 16 + tv) * 32 + hh];
        s1 += CtL[(p * 16 + cv) * 32 + hh];
      }
      s0 += AtL[(int)actL[tbl] * 32 + hh];
      float d0 = dirL[tbl * 4 + 0], d1 = dirL[tbl * 4 + 1];
      float d2 = dirL[tbl * 4 + 2], d3 = dirL[tbl * 4 + 3];
      s1 += d0 * WdL[hh] + d1 * WdL[32 + hh] + d2 * WdL[64 + hh] + d3 * WdL[96 + hh];
      s0 += rewL[tbl] * wrr + dnL[tbl] * wdr;
      float xv = fmaxf(s0 + s1, 0.f);
      xout[(size_t)(tb0 + tbl) * 256 + h0 + hh] = __float2bfloat16(xv);
    }
  }
}

// ---------------- persistent fused LSTM (early publish, split vmcnt) --------
__global__ __launch_bounds__(256, 1) void k_lstm(
    const float* c0, const float* bh, const float* Wpi, const float* Wv,
    float* out, char* ws) {
  __shared__ u16 W2T[65536];            // 128KB: [128 pc][512 k], XOR-swizzled
  __shared__ float WpiL[32][8];         // [j-local][a]; a=6 is Wv
  __shared__ float part[2][4][16][8];   // logits partials, dbuf by t&1
  __shared__ unsigned hstage[2][16 * 36]; // tagged h staging [slot][b][36-pad]

  const u16* xbf = (const u16*)(ws + WS_X);
  unsigned* hdb = (unsigned*)(ws + WS_HDB);  // tagged dwords [2][512 b][256 j]
  const u16* w2src = (const u16*)(ws + WS_W2T);

  const int tid = threadIdx.x;
  const int bid = blockIdx.x;
  const int c = bid & 31;             // cluster (batch slice)
  const int q = bid >> 5;             // hidden chunk (j in [q*32, q*32+32))
  const int b0 = c * 16;
  const int lane = tid & 63, wv = tid >> 6;
  const int G = lane >> 4, bl = lane & 15;

  {  // stage W2T slice (once)
    const s8v* src = (const s8v*)(w2src + (size_t)q * 65536);
    s8v* dst = (s8v*)W2T;
    for (int i = tid; i < 8192; i += 256) dst[i] = src[i];
  }
  {
    int jl = tid >> 3, a = tid & 7;
    int j = q * 32 + jl;
    WpiL[jl][a] = (a < 6) ? Wpi[j * 6 + a] : ((a == 6) ? Wv[j] : 0.f);
  }
  __syncthreads();

  const int jt0 = wv * 2, jt1 = wv * 2 + 1;
  const int jl0 = jt0 * 4 + G, jl1 = jt1 * 4 + G;
  const int myhj0 = q * 32 + jl0, myhj1 = q * 32 + jl1;
  const unsigned swz = ((unsigned)(bl & 7)) << 4;
  const unsigned ab0 = ((unsigned)(jt0 * 16 + bl)) << 10;
  const unsigned ab1 = ((unsigned)(jt1 * 16 + bl)) << 10;

  float bh0r[4], bh1r[4];
#pragma unroll
  for (int r = 0; r < 4; ++r) {
    bh0r[r] = bh[r * 256 + myhj0];
    bh1r[r] = bh[r * 256 + myhj1];
  }
  float cst0 = c0[(size_t)(b0 + bl) * 256 + myhj0];
  float cst1 = c0[(size_t)(b0 + bl) * 256 + myhj1];

  float* out_logits = out;
  float* out_values = out + 393216;
  float* out_cf = out + 458752;
  float* out_hf = out + 589824;

  for (int t = 0; t < 128; ++t) {
    // ---- 1) issue x-frag loads, then poll loads, all inline asm
    s8v xf[8];
    const u16* xr = xbf + ((size_t)t * 512 + (b0 + bl)) * 256 + 8 * G;
#pragma unroll
    for (int ks = 0; ks < 8; ++ks)
      asm volatile("global_load_dwordx4 %0, %1, off"
                   : "=v"(xf[ks]) : "v"(xr + ks * 32));

    U4 qv[16];
    const unsigned* hp = hdb + (size_t)(t & 1) * 131072u +
                         (size_t)(b0 + bl) * 256u + (unsigned)(G * 8);
#pragma unroll
    for (int i = 0; i < 16; ++i) {
      if ((i >> 1) != q || t == 0)   // own chunk comes from LDS when t>0
        asm volatile("global_load_dwordx4 %0, %1, off sc0 sc1"
                     : "=v"(qv[i].v4) : "v"(hp + (i >> 1) * 32 + (i & 1) * 4));
    }
    // x loads (issued first, in-order counter) complete at vmcnt(14);
    // poll loads stay in flight under the x-MFMAs.
    asm volatile("s_waitcnt vmcnt(14)" ::: "memory");
    __builtin_amdgcn_sched_barrier(0);

    // ---- 2) x-MFMAs overlap the first poll flight
    f4v acc0 = {0.f, 0.f, 0.f, 0.f};
    f4v acc1 = {0.f, 0.f, 0.f, 0.f};
#pragma unroll
    for (int ks = 0; ks < 8; ++ks) {
      unsigned k2 = (unsigned)(ks * 64 + G * 16);
      s8v a0 = *(const s8v*)((const char*)W2T + ((ab0 + k2) ^ swz));
      s8v a1 = *(const s8v*)((const char*)W2T + ((ab1 + k2) ^ swz));
      acc0 = __builtin_amdgcn_mfma_f32_16x16x32_bf16(a0, xf[ks], acc0, 0, 0, 0);
      acc1 = __builtin_amdgcn_mfma_f32_16x16x32_bf16(a1, xf[ks], acc1, 0, 0, 0);
    }
    asm volatile("s_waitcnt vmcnt(0)" ::: "memory");
    __builtin_amdgcn_sched_barrier(0);

    // ---- 3) tag check + re-poll (s_sleep backoff, as r8)
    const unsigned tq = (unsigned)t;
    bool ok = true;
#pragma unroll
    for (int i = 0; i < 16; ++i) {
      if ((i >> 1) == q && t != 0) continue;
#pragma unroll
      for (int c2 = 0; c2 < 4; ++c2) ok &= ((qv[i].u[c2] >> 16) == tq);
    }
    while (!ok) {
      __builtin_amdgcn_s_sleep(2);
#pragma unroll
      for (int i = 0; i < 16; ++i) {
        if ((i >> 1) != q || t == 0)
          asm volatile("global_load_dwordx4 %0, %1, off sc0 sc1"
                       : "=v"(qv[i].v4) : "v"(hp + (i >> 1) * 32 + (i & 1) * 4));
      }
      asm volatile("s_waitcnt vmcnt(0)" ::: "memory");
      __builtin_amdgcn_sched_barrier(0);
      ok = true;
#pragma unroll
      for (int i = 0; i < 16; ++i) {
        if ((i >> 1) == q && t != 0) continue;
#pragma unroll
        for (int c2 = 0; c2 < 4; ++c2) ok &= ((qv[i].u[c2] >> 16) == tq);
      }
    }

    // ---- 4) h-MFMAs (own chunk from hstage[t&1])
#pragma unroll
    for (int ks = 0; ks < 8; ++ks) {
      union { s8v v; unsigned u[4]; } bu;
      if (ks == q && t != 0) {
        const unsigned* hs = &hstage[t & 1][bl * 36 + G * 8];
        bu.u[0] = (hs[0] & 0xffffu) | (hs[1] << 16);
        bu.u[1] = (hs[2] & 0xffffu) | (hs[3] << 16);
        bu.u[2] = (hs[4] & 0xffffu) | (hs[5] << 16);
        bu.u[3] = (hs[6] & 0xffffu) | (hs[7] << 16);
      } else {
        const unsigned* pa = qv[ks * 2].u;
        const unsigned* pb = qv[ks * 2 + 1].u;
        bu.u[0] = (pa[0] & 0xffffu) | (pa[1] << 16);
        bu.u[1] = (pa[2] & 0xffffu) | (pa[3] << 16);
        bu.u[2] = (pb[0] & 0xffffu) | (pb[1] << 16);
        bu.u[3] = (pb[2] & 0xffffu) | (pb[3] << 16);
      }
      unsigned k2 = (unsigned)((ks + 8) * 64 + G * 16);
      s8v a0 = *(const s8v*)((const char*)W2T + ((ab0 + k2) ^ swz));
      s8v a1 = *(const s8v*)((const char*)W2T + ((ab1 + k2) ^ swz));
      acc0 = __builtin_amdgcn_mfma_f32_16x16x32_bf16(a0, bu.v, acc0, 0, 0, 0);
      acc1 = __builtin_amdgcn_mfma_f32_16x16x32_bf16(a1, bu.v, acc1, 0, 0, 0);
    }

    // ---- 5) gates (lane-local: acc[r] = gate r of (b0+bl, myhj))
    float zi0 = acc0[0] + bh0r[0], zf0 = acc0[1] + bh0r[1];
    float zg0 = acc0[2] + bh0r[2], zo0 = acc0[3] + bh0r[3];
    float cn0 = sigm_(zf0) * cst0 + sigm_(zi0) * tanh_(zg0);
    float hn0 = sigm_(zo0) * tanh_(cn0);
    cst0 = cn0;
    float zi1 = acc1[0] + bh1r[0], zf1 = acc1[1] + bh1r[1];
    float zg1 = acc1[2] + bh1r[2], zo1 = acc1[3] + bh1r[3];
    float cn1 = sigm_(zf1) * cst1 + sigm_(zi1) * tanh_(zg1);
    float hn1 = sigm_(zo1) * tanh_(cn1);
    cst1 = cn1;

    // ---- 6) EARLY PUBLISH: per-lane tagged sc01 stores straight from regs
    const int wslot = (t + 1) & 1, pt = t & 1;
    if (t < 127) {
      __hip_bfloat16 hb0 = __float2bfloat16(hn0);
      __hip_bfloat16 hb1 = __float2bfloat16(hn1);
      unsigned d0 = ((unsigned)(t + 1) << 16) | (unsigned)*(u16*)&hb0;
      unsigned d1 = ((unsigned)(t + 1) << 16) | (unsigned)*(u16*)&hb1;
      unsigned* hw = hdb + (size_t)wslot * 131072u + (size_t)(b0 + bl) * 256u;
      asm volatile("global_store_dword %0, %1, off sc0 sc1"
                   :: "v"(hw + myhj0), "v"(d0) : "memory");
      asm volatile("global_store_dword %0, %1, off sc0 sc1"
                   :: "v"(hw + myhj1), "v"(d1) : "memory");
      // own-chunk fast path for next step
      hstage[wslot][bl * 36 + jl0] = d0;
      hstage[wslot][bl * 36 + jl1] = d1;
    } else {
      size_t o = (size_t)(b0 + bl) * 256;
      out_cf[o + myhj0] = cst0;
      out_cf[o + myhj1] = cst1;
      out_hf[o + myhj0] = hn0;
      out_hf[o + myhj1] = hn1;
    }

    // ---- 7) logits/value partials (overlaps publish flight)
    float pl[7];
#pragma unroll
    for (int a = 0; a < 7; ++a) {
      float s = hn0 * WpiL[jl0][a] + hn1 * WpiL[jl1][a];
      s += __shfl_xor(s, 16, 64);
      s += __shfl_xor(s, 32, 64);
      pl[a] = s;
    }
    if (lane < 16) {
#pragma unroll
      for (int a = 0; a < 7; ++a) part[pt][wv][bl][a] = pl[a];
    }

    __syncthreads();

    // ---- 8) logits adds (waves 2-3 only; publish already issued)
    if (tid >= 128) {
      int i2 = tid - 128, b_ = i2 >> 3, a_ = i2 & 7;
      if (a_ < 7) {
        float s = part[pt][0][b_][a_] + part[pt][1][b_][a_] +
                  part[pt][2][b_][a_] + part[pt][3][b_][a_];
        if (a_ < 6)
          atomicAdd(out_logits + ((size_t)t * 512 + b0 + b_) * 6 + a_, s);
        else
          atomicAdd(out_values + (size_t)t * 512 + b0 + b_, s);
      }
    }
  }
}

extern "C" void kernel_launch(void* const* d_in, const int* in_sizes, int n_in,
                              void* d_out, int out_size, void* d_ws, size_t ws_size,
                              hipStream_t stream) {
  const int*   obs_img     = (const int*)d_in[0];
  const float* obs_dir     = (const float*)d_in[1];
  const int*   prev_action = (const int*)d_in[2];
  const float* prev_reward = (const float*)d_in[3];
  const float* done        = (const float*)d_in[4];
  const float* c0          = (const float*)d_in[5];
  const float* h0          = (const float*)d_in[6];
  const float* tile_emb    = (const float*)d_in[7];
  const float* color_emb   = (const float*)d_in[8];
  const float* action_emb  = (const float*)d_in[9];
  const float* Wdir        = (const float*)d_in[10];
  const float* bdir        = (const float*)d_in[11];
  const float* W1          = (const float*)d_in[12];
  const float* b1          = (const float*)d_in[13];
  const float* Wx          = (const float*)d_in[14];
  const float* Wh          = (const float*)d_in[15];
  const float* bh          = (const float*)d_in[16];
  const float* Wpi         = (const float*)d_in[17];
  const float* bpi         = (const float*)d_in[18];
  const float* Wv          = (const float*)d_in[19];
  const float* bv          = (const float*)d_in[20];
  (void)in_sizes; (void)n_in; (void)out_size; (void)ws_size;

  char* ws = (char*)d_ws;
  float* out = (float*)d_out;

  // kill stale tags every launch (0xAAAA never matches a real tag 0..128)
  (void)hipMemsetAsync(ws + WS_HDB, 0xAA, 1048576u, stream);
  k_prep<<<3248, 256, 0, stream>>>(tile_emb, color_emb, action_emb, Wdir, bdir,
                                   W1, b1, Wx, Wh, h0, bpi, bv, out, ws);
  k_x<<<512, 512, 0, stream>>>(obs_img, obs_dir, prev_action, prev_reward, done, ws);
  k_lstm<<<256, 256, 0, stream>>>(c0, bh, Wpi, Wv, out, ws);
}